// Round 6
// baseline (72.673 us; speedup 1.0000x reference)
//
#include <hip/hip_runtime.h>

#define D 128
#define CHUNK 32
#define MAX_TYPES 1024
#define MAX_B 8192
#define MARGIN 1.0f

// ws layout (int units)
#define WS_NITEMS 0
#define WS_ORDER  64                     // B ints (slot -> sample idx)
#define WS_ITEMS  8448                   // int4 x <=2048
#define WS_NEEDED ((size_t)(WS_ITEMS + 4 * 2048) * 4)

// ---------------- fused grouping kernel (1 block, 1024 thr) ----------------

__global__ __launch_bounds__(1024) void group_kernel(
    const int* __restrict__ type_r, int* __restrict__ ws,
    float* __restrict__ out, int B, int ntype)
{
    __shared__ int hist[MAX_TYPES];
    __shared__ int typec[MAX_B];
    __shared__ int wsum[16], wsum2[16];
    const int tid = threadIdx.x;
    const int lane = tid & 63;
    const int wv = tid >> 6;

    if (tid == 0) out[0] = 0.0f;
    hist[tid] = 0;
    __syncthreads();

    const int B4 = B >> 2;
    const int4* t4p = (const int4*)type_r;
    for (int i = tid; i < B4; i += 1024) {
        const int4 t = t4p[i];
        typec[i * 4 + 0] = t.x; atomicAdd(&hist[t.x], 1);
        typec[i * 4 + 1] = t.y; atomicAdd(&hist[t.y], 1);
        typec[i * 4 + 2] = t.z; atomicAdd(&hist[t.z], 1);
        typec[i * 4 + 3] = t.w; atomicAdd(&hist[t.w], 1);
    }
    for (int i = (B4 << 2) + tid; i < B; i += 1024) {
        const int t = type_r[i];
        typec[i] = t;
        atomicAdd(&hist[t], 1);
    }
    __syncthreads();

    const int c  = (tid < ntype) ? hist[tid] : 0;
    const int ic = (c + CHUNK - 1) / CHUNK;
    int vc = c, vic = ic;
    #pragma unroll
    for (int off = 1; off < 64; off <<= 1) {
        const int tc  = __shfl_up(vc,  off);
        const int tic = __shfl_up(vic, off);
        if (lane >= off) { vc += tc; vic += tic; }
    }
    if (lane == 63) { wsum[wv] = vc; wsum2[wv] = vic; }
    __syncthreads();
    if (wv == 0 && lane < 16) {
        int a = wsum[lane], b = wsum2[lane];
        #pragma unroll
        for (int off = 1; off < 16; off <<= 1) {
            const int ta = __shfl_up(a, off);
            const int tb = __shfl_up(b, off);
            if (lane >= off) { a += ta; b += tb; }
        }
        wsum[lane] = a; wsum2[lane] = b;
    }
    __syncthreads();
    const int base_c  = (wv ? wsum[wv - 1]  : 0) + vc - c;
    const int base_ic = (wv ? wsum2[wv - 1] : 0) + vic - ic;
    hist[tid] = base_c;                   // scatter cursor
    if (tid < ntype && ic > 0) {
        int4* items = (int4*)(ws + WS_ITEMS);
        for (int k = 0; k < ic; ++k)
            items[base_ic + k] = make_int4(tid, base_c + k * CHUNK,
                                           min(CHUNK, c - k * CHUNK), 0);
    }
    if (tid == 0) ws[WS_NITEMS] = wsum2[15];
    __syncthreads();
    for (int i = tid; i < B; i += 1024) {
        const int p = atomicAdd(&hist[typec[i]], 1);
        ws[WS_ORDER + p] = i;
    }
}

// ---------------- fused projection+score kernel ----------------
// 256 thr = 4 waves. lane: cg = lane&31 (cols cg*4..+3), hl = lane>>5.
// Wave wq + hl own dims [wq*32 + hl*16, +16). T panel: 16 x float4 = 64 VGPR.
// Epilogue for sample j done by wave (j&3) between barrier(j) and barrier(j+1).

#define BFLY6(x) { x += __shfl_xor(x, 1); x += __shfl_xor(x, 2); x += __shfl_xor(x, 4); \
                   x += __shfl_xor(x, 8); x += __shfl_xor(x, 16); x += __shfl_xor(x, 32); }

__device__ __forceinline__ void matvec_store(
    const float4* __restrict__ vb, const float4 t4[16],
    float* __restrict__ paccP, int wq, int cg, int hl)
{
    float4 a0 = make_float4(0.f, 0.f, 0.f, 0.f), a1 = a0, a2 = a0, a3 = a0;
    #pragma unroll
    for (int r = 0; r < 16; ++r) {
        const float4 v = vb[r];      // 2-addr LDS broadcast (free)
        const float4 t = t4[r];
        a0.x = fmaf(t.x, v.x, a0.x); a0.y = fmaf(t.x, v.y, a0.y);
        a0.z = fmaf(t.x, v.z, a0.z); a0.w = fmaf(t.x, v.w, a0.w);
        a1.x = fmaf(t.y, v.x, a1.x); a1.y = fmaf(t.y, v.y, a1.y);
        a1.z = fmaf(t.y, v.z, a1.z); a1.w = fmaf(t.y, v.w, a1.w);
        a2.x = fmaf(t.z, v.x, a2.x); a2.y = fmaf(t.z, v.y, a2.y);
        a2.z = fmaf(t.z, v.z, a2.z); a2.w = fmaf(t.z, v.w, a2.w);
        a3.x = fmaf(t.w, v.x, a3.x); a3.y = fmaf(t.w, v.y, a3.y);
        a3.z = fmaf(t.w, v.z, a3.z); a3.w = fmaf(t.w, v.w, a3.w);
    }
    a0.x += __shfl_xor(a0.x, 32); a0.y += __shfl_xor(a0.y, 32);
    a0.z += __shfl_xor(a0.z, 32); a0.w += __shfl_xor(a0.w, 32);
    a1.x += __shfl_xor(a1.x, 32); a1.y += __shfl_xor(a1.y, 32);
    a1.z += __shfl_xor(a1.z, 32); a1.w += __shfl_xor(a1.w, 32);
    a2.x += __shfl_xor(a2.x, 32); a2.y += __shfl_xor(a2.y, 32);
    a2.z += __shfl_xor(a2.z, 32); a2.w += __shfl_xor(a2.w, 32);
    a3.x += __shfl_xor(a3.x, 32); a3.y += __shfl_xor(a3.y, 32);
    a3.z += __shfl_xor(a3.z, 32); a3.w += __shfl_xor(a3.w, 32);
    if (hl == 0) {
        float* slot = paccP + (wq * 32 + cg) * 20;   // 2-way banks only (free)
        *(float4*)(slot + 0)  = make_float4(a0.x, a1.x, a2.x, a3.x); // ph
        *(float4*)(slot + 4)  = make_float4(a0.y, a1.y, a2.y, a3.y); // pt
        *(float4*)(slot + 8)  = make_float4(a0.z, a1.z, a2.z, a3.z); // nh
        *(float4*)(slot + 12) = make_float4(a0.w, a1.w, a2.w, a3.w); // nt
    }
}

// one pipelined iteration: P=j&1. Commits rows j+1 (RV/RR), prefetches idx j+4
// (into IL/IRL), issues row loads j+3 (from IU/IRU), computes sample j,
// epilogue(j) on wave j&3.
#define PROJ_BODY(J, P, RV, RR, IU, IRU, IL, IRL)                            \
    do {                                                                     \
        if ((J) + 1 < cnt) {                                                 \
            if (ldr) vbuf[!(P)][tid] = RV;                                   \
            else     rbuf[!(P)][t2]  = RR;                                   \
        }                                                                    \
        if ((J) + 4 < cnt) {                                                 \
            const int o_ = ordr[start + (J) + 4];                            \
            IL  = make_int4(pos_h[o_], pos_t[o_], neg_h[o_], neg_t[o_]);     \
            IRL = make_int2(pos_r[o_], neg_r[o_]);                           \
        }                                                                    \
        if ((J) + 3 < cnt) {                                                 \
            if (ldr) {                                                       \
                RV.x = ent[(size_t)IU.x * D + tid];                          \
                RV.y = ent[(size_t)IU.y * D + tid];                          \
                RV.z = ent[(size_t)IU.z * D + tid];                          \
                RV.w = ent[(size_t)IU.w * D + tid];                          \
            } else {                                                         \
                RR.x = rel[(size_t)IRU.x * D + t2];                          \
                RR.y = rel[(size_t)IRU.y * D + t2];                          \
            }                                                                \
        }                                                                    \
        matvec_store(vbuf[(P)] + rowbase, t4, pacc[(P)], wq, cg, hl);        \
        const bool epi_ = (wq == ((J) & 3));                                 \
        float2 er0, er1;                                                     \
        if (epi_) { er0 = rbuf[(P)][lane]; er1 = rbuf[(P)][lane + 64]; }     \
        __syncthreads(); /* pacc[P] ready */                                 \
        if (epi_) {                                                          \
            const float* pc = pacc[(P)];                                     \
            const int b0 = ((lane) >> 2) * 20 + ((lane) & 3);                \
            const int b1 = ((lane + 64) >> 2) * 20 + ((lane + 64) & 3);      \
            const float v00 = pc[b0+0] + pc[640+b0+0] + pc[1280+b0+0] + pc[1920+b0+0]; \
            const float v01 = pc[b1+0] + pc[640+b1+0] + pc[1280+b1+0] + pc[1920+b1+0]; \
            const float v10 = pc[b0+4] + pc[640+b0+4] + pc[1280+b0+4] + pc[1920+b0+4]; \
            const float v11 = pc[b1+4] + pc[640+b1+4] + pc[1280+b1+4] + pc[1920+b1+4]; \
            const float v20 = pc[b0+8] + pc[640+b0+8] + pc[1280+b0+8] + pc[1920+b0+8]; \
            const float v21 = pc[b1+8] + pc[640+b1+8] + pc[1280+b1+8] + pc[1920+b1+8]; \
            const float v30 = pc[b0+12] + pc[640+b0+12] + pc[1280+b0+12] + pc[1920+b0+12]; \
            const float v31 = pc[b1+12] + pc[640+b1+12] + pc[1280+b1+12] + pc[1920+b1+12]; \
            float sph = v00*v00 + v01*v01;                                   \
            float spt = v10*v10 + v11*v11;                                   \
            float snh = v20*v20 + v21*v21;                                   \
            float snt = v30*v30 + v31*v31;                                   \
            float spr = er0.x*er0.x + er1.x*er1.x;                           \
            float snr = er0.y*er0.y + er1.y*er1.y;                           \
            BFLY6(sph); BFLY6(spt); BFLY6(snh);                              \
            BFLY6(snt); BFLY6(spr); BFLY6(snr);                              \
            const float iph = rsqrtf(sph + 1e-12f);                          \
            const float ipt = rsqrtf(spt + 1e-12f);                          \
            const float inh = rsqrtf(snh + 1e-12f);                          \
            const float itn = rsqrtf(snt + 1e-12f);                          \
            const float ipr = rsqrtf(spr + 1e-12f);                          \
            const float inr = rsqrtf(snr + 1e-12f);                          \
            float z = fabsf(v00*iph + er0.x*ipr - v10*ipt)                   \
                    + fabsf(v01*iph + er1.x*ipr - v11*ipt)                   \
                    - fabsf(v20*inh + er0.y*inr - v30*itn)                   \
                    - fabsf(v21*inh + er1.y*inr - v31*itn);                  \
            BFLY6(z);                                                        \
            wl += fmaxf(z + MARGIN, 0.f);                                    \
        }                                                                    \
    } while (0)

__global__ __launch_bounds__(256, 3) void fused_kernel(
    const float* __restrict__ ent,
    const float* __restrict__ rel,
    const float* __restrict__ tmat,
    const int* __restrict__ pos_h,
    const int* __restrict__ pos_t,
    const int* __restrict__ pos_r,
    const int* __restrict__ neg_h,
    const int* __restrict__ neg_t,
    const int* __restrict__ neg_r,
    const int* __restrict__ ws,
    float* __restrict__ out,
    float inv_B)
{
    const int nit = ws[WS_NITEMS];
    if (blockIdx.x >= nit) return;
    const int4 item = ((const int4*)(ws + WS_ITEMS))[blockIdx.x];
    const int type  = item.x;
    const int start = item.y;
    const int cnt   = item.z;

    const int tid  = threadIdx.x;
    const int lane = tid & 63;
    const int wq   = tid >> 6;
    const int cg   = lane & 31;
    const int hl   = lane >> 5;
    const int rowbase = wq * 32 + hl * 16;
    const bool ldr = (tid < 128);
    const int t2 = tid & 127;            // rel loader index (upper threads)

    __shared__ float4 vbuf[2][D];
    __shared__ float2 rbuf[2][D];
    __shared__ float  pacc[2][2560];
    __shared__ float  sred[4];

    float4 t4[16];
    {
        const float* Tp = tmat + (size_t)type * (D * D) + (size_t)rowbase * D + cg * 4;
        #pragma unroll
        for (int r = 0; r < 16; ++r)
            t4[r] = *(const float4*)(Tp + r * D);
    }

    const int* ordr = ws + WS_ORDER;

    // prologue: sample0 -> LDS; rows1 -> slotB; rows2 -> slotA; idx3 -> slotB idx
    float4 rvA = make_float4(0.f,0.f,0.f,0.f), rvB = rvA;
    float2 rrA = make_float2(0.f,0.f), rrB = rrA;
    int4 isA = make_int4(0,0,0,0), isB = isA;
    int2 irA = make_int2(0,0), irB = irA;
    {
        const int o = ordr[start];
        if (ldr) {
            float4 v;
            v.x = ent[(size_t)pos_h[o] * D + tid];
            v.y = ent[(size_t)pos_t[o] * D + tid];
            v.z = ent[(size_t)neg_h[o] * D + tid];
            v.w = ent[(size_t)neg_t[o] * D + tid];
            vbuf[0][tid] = v;
        } else {
            float2 rr;
            rr.x = rel[(size_t)pos_r[o] * D + t2];
            rr.y = rel[(size_t)neg_r[o] * D + t2];
            rbuf[0][t2] = rr;
        }
    }
    if (cnt > 1) {
        const int o = ordr[start + 1];
        if (ldr) {
            rvB.x = ent[(size_t)pos_h[o] * D + tid];
            rvB.y = ent[(size_t)pos_t[o] * D + tid];
            rvB.z = ent[(size_t)neg_h[o] * D + tid];
            rvB.w = ent[(size_t)neg_t[o] * D + tid];
        } else {
            rrB.x = rel[(size_t)pos_r[o] * D + t2];
            rrB.y = rel[(size_t)neg_r[o] * D + t2];
        }
    }
    if (cnt > 2) {
        const int o = ordr[start + 2];
        if (ldr) {
            rvA.x = ent[(size_t)pos_h[o] * D + tid];
            rvA.y = ent[(size_t)pos_t[o] * D + tid];
            rvA.z = ent[(size_t)neg_h[o] * D + tid];
            rvA.w = ent[(size_t)neg_t[o] * D + tid];
        } else {
            rrA.x = rel[(size_t)pos_r[o] * D + t2];
            rrA.y = rel[(size_t)neg_r[o] * D + t2];
        }
    }
    if (cnt > 3) {
        const int o = ordr[start + 3];
        isB = make_int4(pos_h[o], pos_t[o], neg_h[o], neg_t[o]);
        irB = make_int2(pos_r[o], neg_r[o]);
    }
    __syncthreads();   // vbuf[0]/rbuf[0] visible

    float wl = 0.f;
    int j = 0;
    while (true) {
        PROJ_BODY(j, 0, rvB, rrB, isB, irB, isA, irA);
        if (++j >= cnt) break;
        PROJ_BODY(j, 1, rvA, rrA, isA, irA, isB, irB);
        if (++j >= cnt) break;
    }

    __syncthreads();
    if (lane == 0) sred[wq] = wl;
    __syncthreads();
    if (tid == 0)
        atomicAdd(out, (sred[0] + sred[1] + sred[2] + sred[3]) * inv_B);
}

// ---------------- fallback (round-1 per-sample kernel) ----------------

__global__ __launch_bounds__(128) void transr_fallback(
    const float* __restrict__ ent, const float* __restrict__ rel,
    const float* __restrict__ tmat,
    const int* __restrict__ pos_h, const int* __restrict__ pos_t,
    const int* __restrict__ pos_r, const int* __restrict__ pos_type_r,
    const int* __restrict__ neg_h, const int* __restrict__ neg_t,
    const int* __restrict__ neg_r, float* __restrict__ out, int B)
{
    const int b = blockIdx.x;
    const int r = threadIdx.x;
    const int lane = r & 63;
    const int wid = r >> 6;
    __shared__ float4 vcomb[D];
    __shared__ float sred[16];
    vcomb[r] = make_float4(ent[(size_t)pos_h[b]*D + r], ent[(size_t)pos_t[b]*D + r],
                           ent[(size_t)neg_h[b]*D + r], ent[(size_t)neg_t[b]*D + r]);
    const float prr = rel[(size_t)pos_r[b] * D + r];
    const float nrr = rel[(size_t)neg_r[b] * D + r];
    __syncthreads();
    const float* __restrict__ T = tmat + (size_t)pos_type_r[b] * (D * D);
    float aph = 0.f, apt = 0.f, anh = 0.f, ant = 0.f;
    #pragma unroll 8
    for (int d = 0; d < D; ++d) {
        const float t = T[d * D + r];
        const float4 v = vcomb[d];
        aph = fmaf(v.x, t, aph); apt = fmaf(v.y, t, apt);
        anh = fmaf(v.z, t, anh); ant = fmaf(v.w, t, ant);
    }
    float s0 = aph*aph, s1 = apt*apt, s2 = anh*anh, s3 = ant*ant;
    float s4 = prr*prr, s5 = nrr*nrr;
    #pragma unroll
    for (int off = 32; off; off >>= 1) {
        s0 += __shfl_xor(s0, off); s1 += __shfl_xor(s1, off);
        s2 += __shfl_xor(s2, off); s3 += __shfl_xor(s3, off);
        s4 += __shfl_xor(s4, off); s5 += __shfl_xor(s5, off);
    }
    if (lane == 0) {
        sred[wid*8+0]=s0; sred[wid*8+1]=s1; sred[wid*8+2]=s2;
        sred[wid*8+3]=s3; sred[wid*8+4]=s4; sred[wid*8+5]=s5;
    }
    __syncthreads();
    const float iph = rsqrtf(sred[0]+sred[8] +1e-12f);
    const float ipt = rsqrtf(sred[1]+sred[9] +1e-12f);
    const float inh = rsqrtf(sred[2]+sred[10]+1e-12f);
    const float itn = rsqrtf(sred[3]+sred[11]+1e-12f);
    const float ipr = rsqrtf(sred[4]+sred[12]+1e-12f);
    const float inr = rsqrtf(sred[5]+sred[13]+1e-12f);
    float pterm = fabsf(aph*iph + prr*ipr - apt*ipt);
    float nterm = fabsf(anh*inh + nrr*inr - ant*itn);
    #pragma unroll
    for (int off = 32; off; off >>= 1) {
        pterm += __shfl_xor(pterm, off);
        nterm += __shfl_xor(nterm, off);
    }
    __syncthreads();
    if (lane == 0) { sred[wid*2+0] = pterm; sred[wid*2+1] = nterm; }
    __syncthreads();
    if (r == 0)
        atomicAdd(out, fmaxf(sred[0]+sred[2] - sred[1]-sred[3] + MARGIN, 0.f) / (float)B);
}

// ---------------- launch ----------------

extern "C" void kernel_launch(void* const* d_in, const int* in_sizes, int n_in,
                              void* d_out, int out_size, void* d_ws, size_t ws_size,
                              hipStream_t stream) {
    const float* ent  = (const float*)d_in[0];
    const float* rel  = (const float*)d_in[1];
    const float* tmat = (const float*)d_in[2];
    const int* pos_h      = (const int*)d_in[3];
    const int* pos_t      = (const int*)d_in[4];
    const int* pos_r      = (const int*)d_in[5];
    const int* pos_type_r = (const int*)d_in[6];
    const int* neg_h      = (const int*)d_in[7];
    const int* neg_t      = (const int*)d_in[8];
    const int* neg_r      = (const int*)d_in[9];
    float* out = (float*)d_out;
    const int B = in_sizes[3];
    const int ntype = in_sizes[2] / (D * D);

    if (ws_size < WS_NEEDED || ntype > MAX_TYPES || B > MAX_B) {
        hipMemsetAsync(out, 0, sizeof(float), stream);
        transr_fallback<<<B, 128, 0, stream>>>(
            ent, rel, tmat, pos_h, pos_t, pos_r, pos_type_r,
            neg_h, neg_t, neg_r, out, B);
        return;
    }

    int* ws = (int*)d_ws;
    group_kernel<<<1, 1024, 0, stream>>>(pos_type_r, ws, out, B, ntype);
    // worst-case nit <= ntype + B/CHUNK = 1024 + 256
    fused_kernel<<<1280, 256, 0, stream>>>(
        ent, rel, tmat, pos_h, pos_t, pos_r, neg_h, neg_t, neg_r,
        ws, out, 1.0f / (float)B);
}

// Round 7
// 53.435 us; speedup vs baseline: 1.3600x; 1.3600x over previous
//
#include <hip/hip_runtime.h>

#define D 128
#define CHUNK 64
#define MAX_TYPES 1024
#define MAX_B 8192
#define MARGIN 1.0f

// ws layout (int units)
#define WS_NITEMS 0
#define WS_ORDER  64                     // B ints (slot -> sample idx)
#define WS_ITEMS  8448                   // int4 x <=2048
#define WS_NEEDED ((size_t)(WS_ITEMS + 4 * 2048) * 4)

// ---------------- fused grouping kernel (1 block, 1024 thr) ----------------

__global__ __launch_bounds__(1024) void group_kernel(
    const int* __restrict__ type_r, int* __restrict__ ws,
    float* __restrict__ out, int B, int ntype)
{
    __shared__ int hist[MAX_TYPES];
    __shared__ int typec[MAX_B];
    __shared__ int wsum[16], wsum2[16];
    const int tid = threadIdx.x;
    const int lane = tid & 63;
    const int wv = tid >> 6;

    if (tid == 0) out[0] = 0.0f;
    hist[tid] = 0;
    __syncthreads();

    const int B4 = B >> 2;
    const int4* t4p = (const int4*)type_r;
    for (int i = tid; i < B4; i += 1024) {
        const int4 t = t4p[i];
        typec[i * 4 + 0] = t.x; atomicAdd(&hist[t.x], 1);
        typec[i * 4 + 1] = t.y; atomicAdd(&hist[t.y], 1);
        typec[i * 4 + 2] = t.z; atomicAdd(&hist[t.z], 1);
        typec[i * 4 + 3] = t.w; atomicAdd(&hist[t.w], 1);
    }
    for (int i = (B4 << 2) + tid; i < B; i += 1024) {
        const int t = type_r[i];
        typec[i] = t;
        atomicAdd(&hist[t], 1);
    }
    __syncthreads();

    const int c  = (tid < ntype) ? hist[tid] : 0;
    const int ic = (c + CHUNK - 1) / CHUNK;
    int vc = c, vic = ic;
    #pragma unroll
    for (int off = 1; off < 64; off <<= 1) {
        const int tc  = __shfl_up(vc,  off);
        const int tic = __shfl_up(vic, off);
        if (lane >= off) { vc += tc; vic += tic; }
    }
    if (lane == 63) { wsum[wv] = vc; wsum2[wv] = vic; }
    __syncthreads();
    if (wv == 0 && lane < 16) {
        int a = wsum[lane], b = wsum2[lane];
        #pragma unroll
        for (int off = 1; off < 16; off <<= 1) {
            const int ta = __shfl_up(a, off);
            const int tb = __shfl_up(b, off);
            if (lane >= off) { a += ta; b += tb; }
        }
        wsum[lane] = a; wsum2[lane] = b;
    }
    __syncthreads();
    const int base_c  = (wv ? wsum[wv - 1]  : 0) + vc - c;
    const int base_ic = (wv ? wsum2[wv - 1] : 0) + vic - ic;
    hist[tid] = base_c;                   // scatter cursor
    if (tid < ntype && ic > 0) {
        int4* items = (int4*)(ws + WS_ITEMS);
        for (int k = 0; k < ic; ++k)
            items[base_ic + k] = make_int4(tid, base_c + k * CHUNK,
                                           min(CHUNK, c - k * CHUNK), 0);
    }
    if (tid == 0) ws[WS_NITEMS] = wsum2[15];
    __syncthreads();
    for (int i = tid; i < B; i += 1024) {
        const int p = atomicAdd(&hist[typec[i]], 1);
        ws[WS_ORDER + p] = i;
    }
}

// ---------------- fused main kernel: wave-autonomous samples ----------------

#define BFLY6(x) { x += __shfl_xor(x, 1); x += __shfl_xor(x, 2); x += __shfl_xor(x, 4); \
                   x += __shfl_xor(x, 8); x += __shfl_xor(x, 16); x += __shfl_xor(x, 32); }

// Full per-sample matvec + normalize + hinge score, entirely within one wave.
// Lane l owns output cols {l, l+64}. vb: wave-private role-major [4][D] LDS.
__device__ __forceinline__ float sample_score(
    const float* Tl, const float* vb, int l, float4 rl)
{
    float aph0=0.f, aph1=0.f, apt0=0.f, apt1=0.f;
    float anh0=0.f, anh1=0.f, ant0=0.f, ant1=0.f;
    #pragma unroll 2
    for (int d = 0; d < D; d += 4) {
        const float4 vh = *(const float4*)(vb + d);
        const float4 vt = *(const float4*)(vb + D + d);
        const float4 vn = *(const float4*)(vb + 2 * D + d);
        const float4 vm = *(const float4*)(vb + 3 * D + d);
        #pragma unroll
        for (int dd = 0; dd < 4; ++dd) {
            const float ta = Tl[(d + dd) * D + l];        // 2 lanes/bank: free
            const float tb = Tl[(d + dd) * D + l + 64];
            const float h = ((const float*)&vh)[dd];
            const float t = ((const float*)&vt)[dd];
            const float n = ((const float*)&vn)[dd];
            const float m = ((const float*)&vm)[dd];
            aph0 = fmaf(h, ta, aph0); aph1 = fmaf(h, tb, aph1);
            apt0 = fmaf(t, ta, apt0); apt1 = fmaf(t, tb, apt1);
            anh0 = fmaf(n, ta, anh0); anh1 = fmaf(n, tb, anh1);
            ant0 = fmaf(m, ta, ant0); ant1 = fmaf(m, tb, ant1);
        }
    }
    float sph = aph0*aph0 + aph1*aph1;
    float spt = apt0*apt0 + apt1*apt1;
    float snh = anh0*anh0 + anh1*anh1;
    float snt = ant0*ant0 + ant1*ant1;
    float spr = rl.x*rl.x + rl.y*rl.y;
    float snr = rl.z*rl.z + rl.w*rl.w;
    BFLY6(sph); BFLY6(spt); BFLY6(snh); BFLY6(snt); BFLY6(spr); BFLY6(snr);
    const float iph = rsqrtf(sph + 1e-12f);
    const float ipt = rsqrtf(spt + 1e-12f);
    const float inh = rsqrtf(snh + 1e-12f);
    const float itn = rsqrtf(snt + 1e-12f);
    const float ipr = rsqrtf(spr + 1e-12f);
    const float inr = rsqrtf(snr + 1e-12f);
    float z = fabsf(aph0*iph + rl.x*ipr - apt0*ipt)
            + fabsf(aph1*iph + rl.y*ipr - apt1*ipt)
            - fabsf(anh0*inh + rl.z*inr - ant0*itn)
            - fabsf(anh1*inh + rl.w*inr - ant1*itn);
    BFLY6(z);
    return fmaxf(z + MARGIN, 0.f);
}

#define GATHER(O, E0, E1, E2, E3, RL)                                   \
    {                                                                   \
        const size_t b0 = (size_t)pos_h[O] * D, b1 = (size_t)pos_t[O] * D; \
        const size_t b2 = (size_t)neg_h[O] * D, b3 = (size_t)neg_t[O] * D; \
        const size_t r0 = (size_t)pos_r[O] * D, r1 = (size_t)neg_r[O] * D; \
        E0 = *(const float2*)&ent[b0 + 2 * l];                          \
        E1 = *(const float2*)&ent[b1 + 2 * l];                          \
        E2 = *(const float2*)&ent[b2 + 2 * l];                          \
        E3 = *(const float2*)&ent[b3 + 2 * l];                          \
        RL.x = rel[r0 + l]; RL.y = rel[r0 + l + 64];                    \
        RL.z = rel[r1 + l]; RL.w = rel[r1 + l + 64];                    \
    }

#define COMMIT(E0, E1, E2, E3)                   \
    {                                            \
        *(float2*)&vbw[0 * D + 2 * l] = E0;      \
        *(float2*)&vbw[1 * D + 2 * l] = E1;      \
        *(float2*)&vbw[2 * D + 2 * l] = E2;      \
        *(float2*)&vbw[3 * D + 2 * l] = E3;      \
    }

__global__ __launch_bounds__(512, 4) void fused_kernel(
    const float* __restrict__ ent,
    const float* __restrict__ rel,
    const float* __restrict__ tmat,
    const int* __restrict__ pos_h,
    const int* __restrict__ pos_t,
    const int* __restrict__ pos_r,
    const int* __restrict__ neg_h,
    const int* __restrict__ neg_t,
    const int* __restrict__ neg_r,
    const int* __restrict__ ws,
    float* __restrict__ out,
    float inv_B)
{
    const int nit = ws[WS_NITEMS];
    if (blockIdx.x >= nit) return;
    const int4 item = ((const int4*)(ws + WS_ITEMS))[blockIdx.x];
    const int type  = item.x;
    const int start = item.y;
    const int cnt   = item.z;

    const int tid = threadIdx.x;
    const int l   = tid & 63;
    const int w   = tid >> 6;          // wave 0..7

    __shared__ float T_lds[D * D];     // 64 KB, row-major [d][c]
    __shared__ float vbuf[8][4][D];    // 16 KB, per-wave role-major

    // stage T: 8 float4 per thread, coalesced, layout-preserving
    {
        const float4* Tg = (const float4*)(tmat + (size_t)type * (D * D));
        float4* Ts = (float4*)T_lds;
        #pragma unroll
        for (int k = 0; k < 8; ++k)
            Ts[tid + k * 512] = Tg[tid + k * 512];
    }
    __syncthreads();                   // the ONLY barrier before the loop

    const int* ordr = ws + WS_ORDER;
    float* vbw = &vbuf[w][0][0];

    float wl = 0.f;
    int j = w;
    if (j < cnt) {
        float2 e0A, e1A, e2A, e3A, e0B, e1B, e2B, e3B;
        float4 rA = make_float4(0.f,0.f,0.f,0.f), rB = rA;
        int o = ordr[start + j];
        GATHER(o, e0A, e1A, e2A, e3A, rA);
        for (;;) {
            COMMIT(e0A, e1A, e2A, e3A);
            bool more = (j + 8) < cnt;
            if (more) { o = ordr[start + j + 8]; GATHER(o, e0B, e1B, e2B, e3B, rB); }
            wl += sample_score(T_lds, vbw, l, rA);
            if (!more) break;
            j += 8;
            COMMIT(e0B, e1B, e2B, e3B);
            more = (j + 8) < cnt;
            if (more) { o = ordr[start + j + 8]; GATHER(o, e0A, e1A, e2A, e3A, rA); }
            wl += sample_score(T_lds, vbw, l, rB);
            if (!more) break;
            j += 8;
        }
    }

    // block reduction: reuse each wave's private vbuf slot, one atomic/block
    if (l == 0) vbuf[w][0][0] = wl;
    __syncthreads();
    if (tid == 0) {
        float s = 0.f;
        #pragma unroll
        for (int k = 0; k < 8; ++k) s += vbuf[k][0][0];
        atomicAdd(out, s * inv_B);
    }
}

// ---------------- fallback (round-1 per-sample kernel) ----------------

__global__ __launch_bounds__(128) void transr_fallback(
    const float* __restrict__ ent, const float* __restrict__ rel,
    const float* __restrict__ tmat,
    const int* __restrict__ pos_h, const int* __restrict__ pos_t,
    const int* __restrict__ pos_r, const int* __restrict__ pos_type_r,
    const int* __restrict__ neg_h, const int* __restrict__ neg_t,
    const int* __restrict__ neg_r, float* __restrict__ out, int B)
{
    const int b = blockIdx.x;
    const int r = threadIdx.x;
    const int lane = r & 63;
    const int wid = r >> 6;
    __shared__ float4 vcomb[D];
    __shared__ float sred[16];
    vcomb[r] = make_float4(ent[(size_t)pos_h[b]*D + r], ent[(size_t)pos_t[b]*D + r],
                           ent[(size_t)neg_h[b]*D + r], ent[(size_t)neg_t[b]*D + r]);
    const float prr = rel[(size_t)pos_r[b] * D + r];
    const float nrr = rel[(size_t)neg_r[b] * D + r];
    __syncthreads();
    const float* __restrict__ T = tmat + (size_t)pos_type_r[b] * (D * D);
    float aph = 0.f, apt = 0.f, anh = 0.f, ant = 0.f;
    #pragma unroll 8
    for (int d = 0; d < D; ++d) {
        const float t = T[d * D + r];
        const float4 v = vcomb[d];
        aph = fmaf(v.x, t, aph); apt = fmaf(v.y, t, apt);
        anh = fmaf(v.z, t, anh); ant = fmaf(v.w, t, ant);
    }
    float s0 = aph*aph, s1 = apt*apt, s2 = anh*anh, s3 = ant*ant;
    float s4 = prr*prr, s5 = nrr*nrr;
    #pragma unroll
    for (int off = 32; off; off >>= 1) {
        s0 += __shfl_xor(s0, off); s1 += __shfl_xor(s1, off);
        s2 += __shfl_xor(s2, off); s3 += __shfl_xor(s3, off);
        s4 += __shfl_xor(s4, off); s5 += __shfl_xor(s5, off);
    }
    if (lane == 0) {
        sred[wid*8+0]=s0; sred[wid*8+1]=s1; sred[wid*8+2]=s2;
        sred[wid*8+3]=s3; sred[wid*8+4]=s4; sred[wid*8+5]=s5;
    }
    __syncthreads();
    const float iph = rsqrtf(sred[0]+sred[8] +1e-12f);
    const float ipt = rsqrtf(sred[1]+sred[9] +1e-12f);
    const float inh = rsqrtf(sred[2]+sred[10]+1e-12f);
    const float itn = rsqrtf(sred[3]+sred[11]+1e-12f);
    const float ipr = rsqrtf(sred[4]+sred[12]+1e-12f);
    const float inr = rsqrtf(sred[5]+sred[13]+1e-12f);
    float pterm = fabsf(aph*iph + prr*ipr - apt*ipt);
    float nterm = fabsf(anh*inh + nrr*inr - ant*itn);
    #pragma unroll
    for (int off = 32; off; off >>= 1) {
        pterm += __shfl_xor(pterm, off);
        nterm += __shfl_xor(nterm, off);
    }
    __syncthreads();
    if (lane == 0) { sred[wid*2+0] = pterm; sred[wid*2+1] = nterm; }
    __syncthreads();
    if (r == 0)
        atomicAdd(out, fmaxf(sred[0]+sred[2] - sred[1]-sred[3] + MARGIN, 0.f) / (float)B);
}

// ---------------- launch ----------------

extern "C" void kernel_launch(void* const* d_in, const int* in_sizes, int n_in,
                              void* d_out, int out_size, void* d_ws, size_t ws_size,
                              hipStream_t stream) {
    const float* ent  = (const float*)d_in[0];
    const float* rel  = (const float*)d_in[1];
    const float* tmat = (const float*)d_in[2];
    const int* pos_h      = (const int*)d_in[3];
    const int* pos_t      = (const int*)d_in[4];
    const int* pos_r      = (const int*)d_in[5];
    const int* pos_type_r = (const int*)d_in[6];
    const int* neg_h      = (const int*)d_in[7];
    const int* neg_t      = (const int*)d_in[8];
    const int* neg_r      = (const int*)d_in[9];
    float* out = (float*)d_out;
    const int B = in_sizes[3];
    const int ntype = in_sizes[2] / (D * D);

    if (ws_size < WS_NEEDED || ntype > MAX_TYPES || B > MAX_B) {
        hipMemsetAsync(out, 0, sizeof(float), stream);
        transr_fallback<<<B, 128, 0, stream>>>(
            ent, rel, tmat, pos_h, pos_t, pos_r, pos_type_r,
            neg_h, neg_t, neg_r, out, B);
        return;
    }

    int* ws = (int*)d_ws;
    group_kernel<<<1, 1024, 0, stream>>>(pos_type_r, ws, out, B, ntype);
    // worst-case nit <= ntype + B/CHUNK = 1024 + 128
    fused_kernel<<<1280, 512, 0, stream>>>(
        ent, rel, tmat, pos_h, pos_t, pos_r, neg_h, neg_t, neg_r,
        ws, out, 1.0f / (float)B);
}